// Round 4
// baseline (288.279 us; speedup 1.0000x reference)
//
#include <hip/hip_runtime.h>
#include <stdint.h>

typedef unsigned short u16;
typedef unsigned int u32;
typedef __attribute__((ext_vector_type(8))) short bf16x8;   // 8 bf16 = 4 VGPRs (MFMA A/B frag)
typedef __attribute__((ext_vector_type(8))) unsigned short u16x8;
typedef __attribute__((ext_vector_type(4))) float f32x4;
typedef __attribute__((ext_vector_type(4))) int i32x4;

__device__ __forceinline__ u16 f2bf(float f) {
  uint32_t u = __builtin_bit_cast(uint32_t, f);
  u += 0x7fffu + ((u >> 16) & 1u);   // RNE
  return (u16)(u >> 16);
}

// async global->LDS, 16B per lane; LDS dest must be wave-uniform base (+lane*16 implicit)
#define GLD16(g, l)                                                         \
  __builtin_amdgcn_global_load_lds(                                         \
      (const __attribute__((address_space(1))) void*)(g),                   \
      (__attribute__((address_space(3))) void*)(l), 16, 0, 0)

// ---------------- software grid barrier ----------------
// Residency-safe: grid=256 blocks, LDS=64KB -> capacity 2 blocks/CU -> 512 slots,
// so all 256 blocks are resident regardless of placement. Counters zeroed per
// launch by a hipMemsetAsync graph node. __threadfence = agent-scope fence
// (vmcnt drain + L2 wb/inv) -> cross-XCD visibility of phase outputs (G16).
__device__ __forceinline__ void grid_barrier(u32* ctr, u32 nb) {
  __syncthreads();
  if (threadIdx.x == 0) {
    __threadfence();                       // release our phase's global writes
    u32 old = atomicAdd(ctr, 1u);
    if (old + 1u < nb) {
      while (atomicAdd(ctr, 0u) < nb) __builtin_amdgcn_s_sleep(2);
    }
    __threadfence();                       // acquire: invalidate stale L1/L2
  }
  __syncthreads();
}

// ---------------- dequant helper (identical math to verified dequant_w2x) ----------------
__device__ __forceinline__ void deq8(const int* __restrict__ q, const float* __restrict__ s,
                                     const float* __restrict__ z, u16* __restrict__ w, int t) {
  int g = t >> 4;                 // 8 elems/thread, 128 elems/group -> 16 threads/group
  float sc = s[g];
  float zp = z[g];
  i32x4 a = ((const i32x4*)q)[2 * t];
  i32x4 b = ((const i32x4*)q)[2 * t + 1];
  u16x8 o;
  o[0] = f2bf(((float)a[0] - zp) * sc);
  o[1] = f2bf(((float)a[1] - zp) * sc);
  o[2] = f2bf(((float)a[2] - zp) * sc);
  o[3] = f2bf(((float)a[3] - zp) * sc);
  o[4] = f2bf(((float)b[0] - zp) * sc);
  o[5] = f2bf(((float)b[1] - zp) * sc);
  o[6] = f2bf(((float)b[2] - zp) * sc);
  o[7] = f2bf(((float)b[3] - zp) * sc);
  ((u16x8*)w)[t] = o;
}

// ---------------- NT GEMM phase: C[*,N] = A[*,K] * B[N,K]^T (+bias, relu) ----------------
// Byte-identical inner loop to the round-3 verified gemm_bt: 128x128 tile, 4 waves
// 2x2, 4x4 MFMA 16x16x32 bf16 per wave, BK=64 (2 ksubs), 2-deep counted-vmcnt
// pipeline (8 GLD16/stage/wave, steady-state vmcnt(8)), chunk^=(row&7) swizzle
// applied both-sides (pre-swizzled global source + swizzled ds_read offset).
template <bool RELU, bool OUT_BF16, bool ATOMIC>
__device__ __forceinline__ void gemm_phase(const u16* __restrict__ A,
                                           const u16* __restrict__ Bm,
                                           const float* __restrict__ bias,
                                           void* __restrict__ Cout,
                                           int N, int K, int kChunk,
                                           int m0, int n0, int kStart,
                                           u16* As, u16* Bs) {   // each [2*128*64] in LDS
  const int tid = threadIdx.x;
  const int wave = tid >> 6;
  const int lane = tid & 63;
  const int srow = lane >> 3;
  const int schunk = (((lane & 7) ^ (srow & 7)) << 3);   // pre-swizzled source chunk
  const int wm = (wave >> 1) << 6;
  const int wn = (wave & 1) << 6;
  const int quad = lane >> 4;
  const int l15 = lane & 15;
  const int x7 = lane & 7;
  const int c0 = ((quad ^ x7) << 3);                     // ksub 0 read offset
  const int c1 = (((4 | quad) ^ x7) << 3);               // ksub 1 read offset

  const u16* Ab = A + (size_t)(m0 + 32 * wave + srow) * K + kStart + schunk;
  const u16* Bb = Bm + (size_t)(n0 + 32 * wave + srow) * K + kStart + schunk;
  const int ldsW = (32 * wave) * 64;
  const size_t rs8 = (size_t)8 * K;
  const int nT = kChunk >> 6;                            // 32 for both phases here

  f32x4 acc[4][4];
#pragma unroll
  for (int i = 0; i < 4; i++)
#pragma unroll
    for (int j = 0; j < 4; j++) acc[i][j] = (f32x4){0.f, 0.f, 0.f, 0.f};

#define STAGE(bi_, t_)                                                \
  do {                                                                \
    const int ko_ = (t_) << 6;                                        \
    GLD16(Ab + ko_,           As + (bi_) * 8192 + ldsW);              \
    GLD16(Ab + ko_ + rs8,     As + (bi_) * 8192 + ldsW + 512);        \
    GLD16(Ab + ko_ + 2 * rs8, As + (bi_) * 8192 + ldsW + 1024);       \
    GLD16(Ab + ko_ + 3 * rs8, As + (bi_) * 8192 + ldsW + 1536);       \
    GLD16(Bb + ko_,           Bs + (bi_) * 8192 + ldsW);              \
    GLD16(Bb + ko_ + rs8,     Bs + (bi_) * 8192 + ldsW + 512);        \
    GLD16(Bb + ko_ + 2 * rs8, Bs + (bi_) * 8192 + ldsW + 1024);       \
    GLD16(Bb + ko_ + 3 * rs8, Bs + (bi_) * 8192 + ldsW + 1536);       \
  } while (0)

  bf16x8 af0[4], bf0[4], af1[4], bf1[4];
#define LOADFRAGS(bi_)                                                               \
  do {                                                                               \
    _Pragma("unroll") for (int i = 0; i < 4; i++)                                    \
        af0[i] = *(const bf16x8*)&As[(bi_) * 8192 + (wm + i * 16 + l15) * 64 + c0];  \
    _Pragma("unroll") for (int j = 0; j < 4; j++)                                    \
        bf0[j] = *(const bf16x8*)&Bs[(bi_) * 8192 + (wn + j * 16 + l15) * 64 + c0];  \
    _Pragma("unroll") for (int i = 0; i < 4; i++)                                    \
        af1[i] = *(const bf16x8*)&As[(bi_) * 8192 + (wm + i * 16 + l15) * 64 + c1];  \
    _Pragma("unroll") for (int j = 0; j < 4; j++)                                    \
        bf1[j] = *(const bf16x8*)&Bs[(bi_) * 8192 + (wn + j * 16 + l15) * 64 + c1];  \
  } while (0)

#define MFMA_S0()                                                               \
  do {                                                                          \
    _Pragma("unroll") for (int i = 0; i < 4; i++)                               \
        _Pragma("unroll") for (int j = 0; j < 4; j++)                           \
            acc[i][j] = __builtin_amdgcn_mfma_f32_16x16x32_bf16(                \
                af0[i], bf0[j], acc[i][j], 0, 0, 0);                            \
  } while (0)

#define MFMA_S1()                                                               \
  do {                                                                          \
    _Pragma("unroll") for (int i = 0; i < 4; i++)                               \
        _Pragma("unroll") for (int j = 0; j < 4; j++)                           \
            acc[i][j] = __builtin_amdgcn_mfma_f32_16x16x32_bf16(                \
                af1[i], bf1[j], acc[i][j], 0, 0, 0);                            \
  } while (0)

  STAGE(0, 0);
  STAGE(1, 1);

  int bi = 0;
  for (int t = 0; t < nT - 2; ++t) {
    asm volatile("s_waitcnt vmcnt(8)" ::: "memory");
    __builtin_amdgcn_s_barrier();
    LOADFRAGS(bi);
    asm volatile("s_waitcnt lgkmcnt(8)" ::: "memory");
    __builtin_amdgcn_sched_barrier(0);
    MFMA_S0();
    asm volatile("s_waitcnt lgkmcnt(0)" ::: "memory");
    __builtin_amdgcn_sched_barrier(0);
    __builtin_amdgcn_s_barrier();
    STAGE(bi, t + 2);
    MFMA_S1();
    bi ^= 1;
  }
  asm volatile("s_waitcnt vmcnt(8)" ::: "memory");
  __builtin_amdgcn_s_barrier();
  LOADFRAGS(bi);
  asm volatile("s_waitcnt lgkmcnt(8)" ::: "memory");
  __builtin_amdgcn_sched_barrier(0);
  MFMA_S0();
  asm volatile("s_waitcnt lgkmcnt(0)" ::: "memory");
  __builtin_amdgcn_sched_barrier(0);
  MFMA_S1();
  bi ^= 1;
  asm volatile("s_waitcnt vmcnt(0)" ::: "memory");
  __builtin_amdgcn_s_barrier();
  LOADFRAGS(bi);
  asm volatile("s_waitcnt lgkmcnt(8)" ::: "memory");
  __builtin_amdgcn_sched_barrier(0);
  MFMA_S0();
  asm volatile("s_waitcnt lgkmcnt(0)" ::: "memory");
  __builtin_amdgcn_sched_barrier(0);
  MFMA_S1();

#undef STAGE
#undef LOADFRAGS
#undef MFMA_S0
#undef MFMA_S1

  // epilogue: C/D layout col=lane&15, row=quad*4+reg (verified m89/m91)
#pragma unroll
  for (int i = 0; i < 4; i++) {
#pragma unroll
    for (int j = 0; j < 4; j++) {
      const int col = n0 + wn + j * 16 + l15;
      float bv = 0.f;
      if (!ATOMIC) bv = bias[col];
#pragma unroll
      for (int r = 0; r < 4; r++) {
        const int row = m0 + wm + i * 16 + quad * 4 + r;
        float v = acc[i][j][r];
        if (ATOMIC) {
          atomicAdd((float*)Cout + (size_t)row * N + col, v);
        } else {
          v += bv;
          if (RELU) v = v > 0.f ? v : 0.f;
          if (OUT_BF16)
            ((u16*)Cout)[(size_t)row * N + col] = f2bf(v);
          else
            ((float*)Cout)[(size_t)row * N + col] = v;
        }
      }
    }
  }
}

// ---------------- single fused kernel: prep | gemm1 | gemm2 ----------------
__global__ __launch_bounds__(256) void fused_all(
    const float* __restrict__ x,
    const int* __restrict__ q1, const float* __restrict__ s1, const float* __restrict__ z1,
    const float* __restrict__ b1,
    const int* __restrict__ q2, const float* __restrict__ s2, const float* __restrict__ z2,
    const float* __restrict__ b2,
    float* __restrict__ out,
    u16* __restrict__ xb, u16* __restrict__ w1b, u16* __restrict__ hb, u16* __restrict__ w2b,
    u32* bars) {
  __shared__ u16 As[2 * 128 * 64];   // 32 KB, shared by both GEMM phases
  __shared__ u16 Bs[2 * 128 * 64];   // 32 KB  (total 64 KB -> 2 blocks/CU capacity)

  const int gstride = 256 * 256;
  const int base = blockIdx.x * 256 + threadIdx.x;

  // ---- phase P: all elementwise prep (independent streams, grid-stride) ----
  // cvt x: 512*2048/8 = 131072 items
  for (int t = base; t < 131072; t += gstride) {
    f32x4 a = ((const f32x4*)x)[2 * t];
    f32x4 b = ((const f32x4*)x)[2 * t + 1];
    u16x8 o;
    o[0] = f2bf(a[0]); o[1] = f2bf(a[1]); o[2] = f2bf(a[2]); o[3] = f2bf(a[3]);
    o[4] = f2bf(b[0]); o[5] = f2bf(b[1]); o[6] = f2bf(b[2]); o[7] = f2bf(b[3]);
    ((u16x8*)xb)[t] = o;
  }
  // dequant w1: 8192*2048/8 = 2097152 items
  for (int t = base; t < 2097152; t += gstride) deq8(q1, s1, z1, w1b, t);
  // dequant w2: 2048*8192/8 = 2097152 items
  for (int t = base; t < 2097152; t += gstride) deq8(q2, s2, z2, w2b, t);
  // bias broadcast into out: 512*2048/4 = 262144 f32x4 items (covers every element)
  for (int t = base; t < 262144; t += gstride) {
    ((f32x4*)out)[t] = *(const f32x4*)(b2 + ((t * 4) & 2047));
  }

  grid_barrier(bars + 0, gridDim.x);

  // ---- phase 1: h = relu(x @ w1^T + b1), bf16 out. 256 blocks = 64n x 4m ----
  gemm_phase<true, true, false>(xb, w1b, b1, hb,
                                /*N=*/8192, /*K=*/2048, /*kChunk=*/2048,
                                /*m0=*/(blockIdx.x >> 6) << 7,
                                /*n0=*/(blockIdx.x & 63) << 7,
                                /*kStart=*/0, As, Bs);

  grid_barrier(bars + 1, gridDim.x);

  // ---- phase 2: out += h @ w2^T (split-K=4 atomic; bias pre-added in phase P).
  //      256 blocks = 16n x 4m x 4z ----
  gemm_phase<false, false, true>(hb, w2b, nullptr, out,
                                 /*N=*/2048, /*K=*/8192, /*kChunk=*/2048,
                                 /*m0=*/((blockIdx.x >> 4) & 3) << 7,
                                 /*n0=*/(blockIdx.x & 15) << 7,
                                 /*kStart=*/(blockIdx.x >> 6) << 11, As, Bs);
}

// ---------------- launch ----------------

extern "C" void kernel_launch(void* const* d_in, const int* in_sizes, int n_in,
                              void* d_out, int out_size, void* d_ws, size_t ws_size,
                              hipStream_t stream) {
  const float* x  = (const float*)d_in[0];
  const int*   q1 = (const int*)d_in[1];
  const float* s1 = (const float*)d_in[2];
  const float* z1 = (const float*)d_in[3];
  const float* b1 = (const float*)d_in[4];
  const int*   q2 = (const int*)d_in[5];
  const float* s2 = (const float*)d_in[6];
  const float* z2 = (const float*)d_in[7];
  const float* b2 = (const float*)d_in[8];
  float* out = (float*)d_out;

  char* ws = (char*)d_ws;
  u16* xb  = (u16*)(ws);                                   //  2 MB: x bf16 [512][2048]
  u16* w1b = (u16*)(ws + (size_t)2 * 1024 * 1024);         // 32 MB: w1 bf16 [8192][2048]
  u16* hb  = (u16*)(ws + (size_t)34 * 1024 * 1024);        //  8 MB: h bf16 [512][8192]
  u16* w2b = (u16*)(ws + (size_t)42 * 1024 * 1024);        // 32 MB: w2 bf16 [2048][8192]
  u32* bars = (u32*)(ws + (size_t)74 * 1024 * 1024);       // 8 B: grid-barrier counters

  // zero barrier counters (graph node, ordered before the kernel on this stream)
  hipMemsetAsync(bars, 0, 2 * sizeof(u32), stream);

  // one kernel: prep | barrier | gemm1 | barrier | gemm2
  fused_all<<<256, 256, 0, stream>>>(x, q1, s1, z1, b1, q2, s2, z2, b2,
                                     out, xb, w1b, hb, w2b, bars);
}